// Round 16
// baseline (219.507 us; speedup 1.0000x reference)
//
#include <hip/hip_runtime.h>
#include <stdint.h>

// Problem: B=2, S=2048, D=1024, H=16, DH=64. fp32 in/out, bf16 MFMA inside.

typedef __attribute__((ext_vector_type(8))) short bf16x8;   // 8 bf16 = 4 VGPR
typedef __attribute__((ext_vector_type(4))) float f32x4;    // MFMA C/D

__device__ __forceinline__ uint16_t f2bf(float f) {
  union { float f; uint32_t u; } c; c.f = f;
  uint32_t u = c.u;
  return (uint16_t)((u + 0x7fffu + ((u >> 16) & 1u)) >> 16);  // RNE
}

__device__ __forceinline__ uint32_t cvtpk_bf16(float lo, float hi) {
  uint32_t r;
  asm("v_cvt_pk_bf16_f32 %0, %1, %2" : "=v"(r) : "v"(lo), "v"(hi));
  return r;  // [15:0]=bf16(lo), [31:16]=bf16(hi), RNE
}

__device__ __forceinline__ void gload_lds16(const void* g, void* l) {
  __builtin_amdgcn_global_load_lds(
      (const __attribute__((address_space(1))) uint32_t*)g,
      (__attribute__((address_space(3))) uint32_t*)l, 16, 0, 0);
}

// Stage 8 rows x 64 cols (bf16) into LDS tile rows [r0..r0+8), pitch 128B.
// XOR-swizzle: element (row,col) at byte row*128 + ((col/8)*16 ^ ((row&7)<<4)) + (col%8)*2.
// global_load_lds writes linearly (base + lane*16), so we pre-swizzle the SOURCE granule.
__device__ __forceinline__ void stage8(const uint16_t* gbase, int pitch,
                                       uint16_t* lds_r0, int lane) {
  int r = lane >> 3;
  int gcol = lane & 7;
  int gsrc = gcol ^ r;
  const uint16_t* src = gbase + (size_t)r * pitch + gsrc * 8;
  gload_lds16(src, lds_r0);
}

// Read an 8-element k-contiguous MFMA fragment from a swizzled [rows][64] bf16 LDS tile.
__device__ __forceinline__ bf16x8 frag_read(const uint16_t* tile, int row, int granule) {
  int off = row * 128 + ((granule << 4) ^ ((row & 7) << 4));
  return *(const bf16x8*)((const char*)tile + off);
}

// ---------------- kernel 0: fused prep = fp32->bf16 convert (q, kv) + W transpose ----------------
// grid (2048, 3): y=0 convert q block x; y=1 convert kv block x; y=2 (x<768) wtrans.
__global__ __launch_bounds__(256) void k_prep(const float* __restrict__ q,
                                              const float* __restrict__ kv,
                                              const float* __restrict__ Wq,
                                              const float* __restrict__ Wk,
                                              const float* __restrict__ Wv,
                                              uint16_t* __restrict__ oq,
                                              uint16_t* __restrict__ okv,
                                              uint16_t* __restrict__ Wt) {
  __shared__ uint16_t t[64][72];
  int y = blockIdx.y;
  int tid = threadIdx.x;
  if (y < 2) {
    const float* src = y ? kv : q;
    uint16_t* dst = y ? okv : oq;
    size_t i = ((size_t)blockIdx.x * 256 + tid) * 8;
    float4 a = *(const float4*)(src + i);
    float4 bb = *(const float4*)(src + i + 4);
    uint16_t r[8];
    r[0] = f2bf(a.x); r[1] = f2bf(a.y); r[2] = f2bf(a.z); r[3] = f2bf(a.w);
    r[4] = f2bf(bb.x); r[5] = f2bf(bb.y); r[6] = f2bf(bb.z); r[7] = f2bf(bb.w);
    *(uint4*)(dst + i) = *(uint4*)r;
    return;
  }
  int x = blockIdx.x;
  if (x >= 768) return;
  int by = x >> 4;                        // 0..47 = mat*16 + h
  int bx = x & 15;                        // d-block
  int mat = by >> 4;
  int h = by & 15;
  int d0 = bx * 64;
  const float* W = (mat == 0) ? Wq : (mat == 1) ? Wk : Wv;
  for (int p = 0; p < 4; p++) {
    int idx = tid + p * 256;
    int row = idx >> 4;
    int c4 = idx & 15;
    float4 v = *(const float4*)(W + ((size_t)h * 1024 + d0 + row) * 64 + c4 * 4);
    t[c4 * 4 + 0][row] = f2bf(v.x);
    t[c4 * 4 + 1][row] = f2bf(v.y);
    t[c4 * 4 + 2][row] = f2bf(v.z);
    t[c4 * 4 + 3][row] = f2bf(v.w);
  }
  __syncthreads();
  int n = tid >> 2, dc = tid & 3;
  uint16_t tmp[16];
  for (int i = 0; i < 16; i++) tmp[i] = t[n][dc * 16 + i];
  uint16_t* dst = Wt + ((size_t)(mat * 16 + h) * 64 + n) * 1024 + d0 + dc * 16;
  *(uint4*)(dst) = *(uint4*)(tmp);
  *(uint4*)(dst + 8) = *(uint4*)(tmp + 8);
}

// ---------------- kernel 1: QKV projection GEMM (two heads per block) ----------------
__global__ __launch_bounds__(256, 2) void k_proj(const uint16_t* __restrict__ Xq,
                                                 const uint16_t* __restrict__ Xkv,
                                                 const uint16_t* __restrict__ Wt,
                                                 const float* __restrict__ bq,
                                                 const float* __restrict__ bk,
                                                 const float* __restrict__ bv,
                                                 uint16_t* __restrict__ Qm,
                                                 uint16_t* __restrict__ Km,
                                                 uint16_t* __restrict__ Vtm) {
  __shared__ uint16_t At[2][128 * 64];
  __shared__ uint16_t Bt[2][128 * 64];
  int mb = blockIdx.x;
  int mat = blockIdx.y / 8;
  int h0 = (blockIdx.y % 8) * 2;
  int tid = threadIdx.x, w = tid >> 6, lane = tid & 63;
  const uint16_t* X = (mat == 0) ? Xq : Xkv;
  const uint16_t* Wh = Wt + (size_t)(mat * 16 + h0) * (64 * 1024);
  const float* bias = (mat == 0) ? bq : (mat == 1) ? bk : bv;
  int m0 = mb * 128;
  int rgrp = lane >> 4, cl = lane & 15;

  f32x4 acc[2][8];
#pragma unroll
  for (int mf = 0; mf < 2; mf++)
#pragma unroll
    for (int nf = 0; nf < 8; nf++)
#pragma unroll
      for (int j = 0; j < 4; j++) acc[mf][nf][j] = 0.0f;

#pragma unroll
  for (int i = 0; i < 4; i++) {
    int r0 = w * 32 + i * 8;
    stage8(X + (size_t)(m0 + r0) * 1024, 1024, &At[0][r0 * 64], lane);
    stage8(Wh + (size_t)r0 * 1024, 1024, &Bt[0][r0 * 64], lane);
  }

  for (int kt = 0; kt < 16; kt++) {
    __syncthreads();
    if (kt < 15) {
      int nb = (kt + 1) & 1, k0 = (kt + 1) * 64;
#pragma unroll
      for (int i = 0; i < 4; i++) {
        int r0 = w * 32 + i * 8;
        stage8(X + (size_t)(m0 + r0) * 1024 + k0, 1024, &At[nb][r0 * 64], lane);
        stage8(Wh + (size_t)r0 * 1024 + k0, 1024, &Bt[nb][r0 * 64], lane);
      }
    }
    const uint16_t* a_t = At[kt & 1];
    const uint16_t* b_t = Bt[kt & 1];
    bf16x8 af[2][2], bfr[8][2];
#pragma unroll
    for (int mf = 0; mf < 2; mf++)
#pragma unroll
      for (int ks = 0; ks < 2; ks++)
        af[mf][ks] = frag_read(a_t, w * 32 + mf * 16 + cl, ks * 4 + rgrp);
#pragma unroll
    for (int nf = 0; nf < 8; nf++)
#pragma unroll
      for (int ks = 0; ks < 2; ks++)
        bfr[nf][ks] = frag_read(b_t, nf * 16 + cl, ks * 4 + rgrp);
    __builtin_amdgcn_s_setprio(1);
#pragma unroll
    for (int mf = 0; mf < 2; mf++)
#pragma unroll
      for (int nf = 0; nf < 8; nf++)
#pragma unroll
        for (int ks = 0; ks < 2; ks++)
          acc[mf][nf] = __builtin_amdgcn_mfma_f32_16x16x32_bf16(af[mf][ks], bfr[nf][ks], acc[mf][nf], 0, 0, 0);
    __builtin_amdgcn_s_setprio(0);
  }

#pragma unroll
  for (int mf = 0; mf < 2; mf++)
#pragma unroll
    for (int nf = 0; nf < 8; nf++) {
      int col = nf * 16 + cl;
      int hh = h0 + (col >> 6);
      int c = col & 63;
      float bb = bias[hh * 64 + c];
      if (mat < 2) {
        uint16_t* dstbuf = (mat == 0) ? Qm : Km;
#pragma unroll
        for (int j = 0; j < 4; j++) {
          int row = m0 + w * 32 + mf * 16 + rgrp * 4 + j;
          int b = row >> 11, s = row & 2047;
          dstbuf[((size_t)(b * 16 + hh) * 2048 + s) * 64 + c] = f2bf(acc[mf][nf][j] + bb);
        }
      } else {
        int row0 = m0 + w * 32 + mf * 16 + rgrp * 4;
        int b = row0 >> 11, s0 = row0 & 2047;
        uint16_t pk[4];
#pragma unroll
        for (int j = 0; j < 4; j++) pk[j] = f2bf(acc[mf][nf][j] + bb);
        uint16_t* dst = Vtm + ((size_t)(b * 16 + hh) * 64 + c) * 2048 + s0;
        *(uint64_t*)dst = *(uint64_t*)pk;
      }
    }
}

// ---------------- kernel 1b: mask nonzero partial bitmasks, streaming layout ----------------
// 256 blocks: idx -> b = idx>>7, rg = idx&127 (16-row group). Each block streams a
// CONTIGUOUS 128KB chunk (16 q-rows x 2048 t) and emits one 32-bit mask: bit tt set
// if any nonzero in t-columns [tt*64, tt*64+64). One word per block -- no atomics.
__global__ __launch_bounds__(256) void k_maskflag(const float* __restrict__ mask,
                                                  uint32_t* __restrict__ flagsP) {
  __shared__ uint32_t wm[4];
  int idx = blockIdx.x;
  int b = idx >> 7, rg = idx & 127;
  const float* base = mask + ((size_t)b * 2048 + rg * 16) * 2048;
  int tid = threadIdx.x;
  uint32_t m = 0;
  for (int it = 0; it < 32; it++) {
    int lin = it * 256 + tid;             // float4 index within chunk, 0..8191
    float4 v = *(const float4*)(base + (size_t)lin * 4);
    int tt = ((lin * 4) & 2047) >> 6;
    if ((v.x != 0.0f) | (v.y != 0.0f) | (v.z != 0.0f) | (v.w != 0.0f)) m |= (1u << tt);
  }
#pragma unroll
  for (int d = 1; d < 64; d <<= 1) m |= (uint32_t)__shfl_xor((int)m, d, 64);
  if ((tid & 63) == 0) wm[tid >> 6] = m;
  __syncthreads();
  if (tid == 0) flagsP[idx] = wm[0] | wm[1] | wm[2] | wm[3];
}

// ---------------- kernel 2: flash attention v16 = R15 + V-direct-from-global ----------------
// 1024 blocks (LDS 24KB), 4 waves x 16 q-rows. V fragments come straight from global
// (L2-resident via XCD-local bh map) using R7's validated pairing: A elem e at lane
// (rgrp,cl) is t = t0+32ks+8rgrp+e, matching frag_read(Pw, cl, ks*4+rgrp) exactly.
// Removes V staging (8KB LDS wr) + 32KB LDS rd per block-tile (-42% LDS traffic).
// Issue order: mask -> V globals -> staging (vmcnt retires oldest-first, so each
// wait point tolerates the newer loads remaining in flight).
__global__ __launch_bounds__(256, 2) void k_attn(const uint16_t* __restrict__ Qm,
                                                 const uint16_t* __restrict__ Km,
                                                 const uint16_t* __restrict__ Vtm,
                                                 const float* __restrict__ mask,
                                                 const uint32_t* __restrict__ flagsP,
                                                 float* __restrict__ out) {
  __shared__ uint16_t Kt[2][64 * 64];     // 16 KB
  __shared__ uint16_t Pt[4][16 * 64];     // 8 KB
  int bid = blockIdx.x;
  int xcd = bid & 7, jj = bid >> 3;       // jj 0..127
  int bh = xcd * 4 + (jj & 3);            // 4 bh per XCD (K+V 2MB resident in its L2)
  int qb = jj >> 2;                       // 0..31
  int b = bh >> 4, h = bh & 15;
  int tid = threadIdx.x, w = tid >> 6, lane = tid & 63;
  int q0 = qb * 64 + w * 16;              // 16 q-rows per wave
  int rgrp = lane >> 4, cl = lane & 15;
  const uint16_t* Qbh = Qm + (size_t)bh * (2048 * 64);
  const uint16_t* Kbh = Km + (size_t)bh * (2048 * 64);
  const uint16_t* Vbh = Vtm + (size_t)bh * (64 * 2048);
  const float* mrp = mask + ((size_t)b * 2048 + (q0 + cl)) * 2048;
  uint16_t* Pw = Pt[w];

  const float L2E  = 1.4426950408889634f;
  const float SCL2 = 0.125f * 1.4426950408889634f;
  const float SH2  = -2.0f * 1.4426950408889634f;  // fixed shift: p = exp(S' - 2)

  // mask-tile bits for this block's 64 q-rows: OR of 4 row-group partials
  const uint32_t* fp = flagsP + b * 128 + qb * 4;
  uint32_t bits = fp[0] | fp[1] | fp[2] | fp[3];

  // Q fragments (B-operand of swapped QK^T), registers for all tiles
  bf16x8 qfr[2];
#pragma unroll
  for (int ks = 0; ks < 2; ks++)
    qfr[ks] = *(const bf16x8*)(Qbh + (size_t)(q0 + cl) * 64 + (ks * 4 + rgrp) * 8);

  f32x4 oacc[4];
  float lrow = 0.0f;
#pragma unroll
  for (int dhf = 0; dhf < 4; dhf++)
#pragma unroll
    for (int j = 0; j < 4; j++) oacc[dhf][j] = 0.0f;

  // prologue: stage K tile 0 (rows w*16 .. w*16+15 per wave)
#pragma unroll
  for (int i = 0; i < 2; i++) {
    int r0 = w * 16 + i * 8;
    stage8(Kbh + (size_t)r0 * 64, 64, &Kt[0][r0 * 64], lane);
  }

  for (int ti = 0; ti < 32; ti++) {
    __syncthreads();           // Kt[ti&1] staged; prev tile's LDS reads done
    int t0 = ti * 64;
    bool hasmask = (bits >> ti) & 1;      // wave-uniform

    // mask loads FIRST (oldest in vmcnt queue), skipped when tile all-zero
    float4 mv[4];
    if (hasmask) {
#pragma unroll
      for (int tf = 0; tf < 4; tf++)
        mv[tf] = *(const float4*)(mrp + t0 + tf * 16 + rgrp * 4);
    }

    // V fragments direct from global (L2-hot), issued before staging so the PV
    // wait leaves next-tile staging in flight (R7-validated pairing: t = 32ks+8rgrp+e)
    bf16x8 vf[4][2];
#pragma unroll
    for (int dhf = 0; dhf < 4; dhf++)
#pragma unroll
      for (int ks = 0; ks < 2; ks++)
        vf[dhf][ks] = *(const bf16x8*)(Vbh + (size_t)(dhf * 16 + cl) * 2048 + t0 + (ks * 4 + rgrp) * 8);

    // stage next K tile (stays in flight until next barrier)
    if (ti < 31) {
      int nb = (ti + 1) & 1, t0n = t0 + 64;
#pragma unroll
      for (int i = 0; i < 2; i++) {
        int r0 = w * 16 + i * 8;
        stage8(Kbh + (size_t)(t0n + r0) * 64, 64, &Kt[nb][r0 * 64], lane);
      }
    }
    const uint16_t* kt = Kt[ti & 1];

    // S^T = K Q^T : lane holds S[q=cl][t=tf*16+rgrp*4+j]
    f32x4 sc[4];
#pragma unroll
    for (int tf = 0; tf < 4; tf++)
#pragma unroll
      for (int j = 0; j < 4; j++) sc[tf][j] = 0.0f;
    bf16x8 kf[4][2];
#pragma unroll
    for (int tf = 0; tf < 4; tf++)
#pragma unroll
      for (int ks = 0; ks < 2; ks++)
        kf[tf][ks] = frag_read(kt, tf * 16 + cl, ks * 4 + rgrp);
    __builtin_amdgcn_s_setprio(1);
#pragma unroll
    for (int tf = 0; tf < 4; tf++)
#pragma unroll
      for (int ks = 0; ks < 2; ks++)
        sc[tf] = __builtin_amdgcn_mfma_f32_16x16x32_bf16(kf[tf][ks], qfr[ks], sc[tf], 0, 0, 0);
    __builtin_amdgcn_s_setprio(0);

    // scale+mask only when needed; otherwise fold 0.125 into the exp2 slope
    float eA = L2E;
    if (hasmask) {
#pragma unroll
      for (int tf = 0; tf < 4; tf++) {
        sc[tf][0] = fmaf(sc[tf][0], 0.125f, mv[tf].x);
        sc[tf][1] = fmaf(sc[tf][1], 0.125f, mv[tf].y);
        sc[tf][2] = fmaf(sc[tf][2], 0.125f, mv[tf].z);
        sc[tf][3] = fmaf(sc[tf][3], 0.125f, mv[tf].w);
      }
    } else {
      eA = SCL2;
    }

    // fixed-max: P = exp2(sc*eA + SH2); per-lane l accumulation; pack; b64 writes
#pragma unroll
    for (int tf = 0; tf < 4; tf++) {
      float p0 = __builtin_amdgcn_exp2f(fmaf(sc[tf][0], eA, SH2));
      float p1 = __builtin_amdgcn_exp2f(fmaf(sc[tf][1], eA, SH2));
      float p2 = __builtin_amdgcn_exp2f(fmaf(sc[tf][2], eA, SH2));
      float p3 = __builtin_amdgcn_exp2f(fmaf(sc[tf][3], eA, SH2));
      lrow += (p0 + p1) + (p2 + p3);
      uint2 pv;
      pv.x = cvtpk_bf16(p0, p1);
      pv.y = cvtpk_bf16(p2, p3);
      int off = cl * 128 + ((((tf * 2 + (rgrp >> 1)) << 4)) ^ ((cl & 7) << 4)) + (rgrp & 1) * 8;
      *(uint2*)((char*)Pw + off) = pv;
    }

    // order P stores before P fragment loads (same-wave DS ops are in-order in HW)
    asm volatile("" ::: "memory");

    // O^T += V^T P : A = V^T rows (dh, direct-global), B = P rows (q), k = t
    bf16x8 pf[2];
#pragma unroll
    for (int ks = 0; ks < 2; ks++)
      pf[ks] = frag_read(Pw, cl, ks * 4 + rgrp);
    __builtin_amdgcn_s_setprio(1);
#pragma unroll
    for (int dhf = 0; dhf < 4; dhf++)
#pragma unroll
      for (int ks = 0; ks < 2; ks++)
        oacc[dhf] = __builtin_amdgcn_mfma_f32_16x16x32_bf16(vf[dhf][ks], pf[ks], oacc[dhf], 0, 0, 0);
    __builtin_amdgcn_s_setprio(0);
  }

  // epilogue: reduce l across the 4 rgrp lanes (same q), then write out
  lrow += __shfl_xor(lrow, 16, 64);
  lrow += __shfl_xor(lrow, 32, 64);
  float inv = __builtin_amdgcn_rcpf(lrow);
  float* orow = out + ((size_t)b * 2048 + (q0 + cl)) * 1024 + h * 64;
#pragma unroll
  for (int dhf = 0; dhf < 4; dhf++) {
    float4 o;
    o.x = oacc[dhf][0] * inv;
    o.y = oacc[dhf][1] * inv;
    o.z = oacc[dhf][2] * inv;
    o.w = oacc[dhf][3] * inv;
    *(float4*)(orow + dhf * 16 + rgrp * 4) = o;
  }
}

extern "C" void kernel_launch(void* const* d_in, const int* in_sizes, int n_in,
                              void* d_out, int out_size, void* d_ws, size_t ws_size,
                              hipStream_t stream) {
  const float* q    = (const float*)d_in[0];
  const float* kv   = (const float*)d_in[1];
  const float* mask = (const float*)d_in[2];
  const float* Wq   = (const float*)d_in[3];
  const float* bq   = (const float*)d_in[4];
  const float* Wk   = (const float*)d_in[5];
  const float* bk   = (const float*)d_in[6];
  const float* Wv   = (const float*)d_in[7];
  const float* bv   = (const float*)d_in[8];
  float* out = (float*)d_out;

  // workspace (bf16 elems): Xq, Xkv, Q, K, Vt (4,194,304 each), Wt (3,145,728).
  // After k_proj, Xq is dead -> mask partial bitmasks (256 u32) overlay its start.
  uint16_t* Xq  = (uint16_t*)d_ws;
  uint16_t* Xkv = Xq + 4194304;
  uint16_t* Qm  = Xkv + 4194304;
  uint16_t* Km  = Qm + 4194304;
  uint16_t* Vtm = Km + 4194304;
  uint16_t* Wt  = Vtm + 4194304;
  uint32_t* flagsP = (uint32_t*)Xq;

  hipLaunchKernelGGL(k_prep, dim3(2048, 3), dim3(256), 0, stream,
                     q, kv, Wq, Wk, Wv, Xq, Xkv, Wt);
  hipLaunchKernelGGL(k_proj, dim3(32, 24), dim3(256), 0, stream,
                     Xq, Xkv, Wt, bq, bk, bv, Qm, Km, Vtm);
  hipLaunchKernelGGL(k_maskflag, dim3(256), dim3(256), 0, stream, mask, flagsP);
  hipLaunchKernelGGL(k_attn, dim3(1024), dim3(256), 0, stream,
                     Qm, Km, Vtm, mask, flagsP, out);
}

// Round 17
// 114.507 us; speedup vs baseline: 1.9170x; 1.9170x over previous
//
#include <hip/hip_runtime.h>
#include <stdint.h>

// Problem: B=2, S=2048, D=1024, H=16, DH=64. fp32 in/out, bf16 MFMA inside.

typedef __attribute__((ext_vector_type(8))) short bf16x8;   // 8 bf16 = 4 VGPR
typedef __attribute__((ext_vector_type(4))) float f32x4;    // MFMA C/D

__device__ __forceinline__ uint16_t f2bf(float f) {
  union { float f; uint32_t u; } c; c.f = f;
  uint32_t u = c.u;
  return (uint16_t)((u + 0x7fffu + ((u >> 16) & 1u)) >> 16);  // RNE
}

__device__ __forceinline__ uint32_t cvtpk_bf16(float lo, float hi) {
  uint32_t r;
  asm("v_cvt_pk_bf16_f32 %0, %1, %2" : "=v"(r) : "v"(lo), "v"(hi));
  return r;  // [15:0]=bf16(lo), [31:16]=bf16(hi), RNE
}

__device__ __forceinline__ void gload_lds16(const void* g, void* l) {
  __builtin_amdgcn_global_load_lds(
      (const __attribute__((address_space(1))) uint32_t*)g,
      (__attribute__((address_space(3))) uint32_t*)l, 16, 0, 0);
}

// Stage 8 rows x 64 cols (bf16) into LDS tile rows [r0..r0+8), pitch 128B.
// XOR-swizzle: element (row,col) at byte row*128 + ((col/8)*16 ^ ((row&7)<<4)) + (col%8)*2.
// global_load_lds writes linearly (base + lane*16), so we pre-swizzle the SOURCE granule.
__device__ __forceinline__ void stage8(const uint16_t* gbase, int pitch,
                                       uint16_t* lds_r0, int lane) {
  int r = lane >> 3;
  int gcol = lane & 7;
  int gsrc = gcol ^ r;
  const uint16_t* src = gbase + (size_t)r * pitch + gsrc * 8;
  gload_lds16(src, lds_r0);
}

// Read an 8-element k-contiguous MFMA fragment from a swizzled [rows][64] bf16 LDS tile.
__device__ __forceinline__ bf16x8 frag_read(const uint16_t* tile, int row, int granule) {
  int off = row * 128 + ((granule << 4) ^ ((row & 7) << 4));
  return *(const bf16x8*)((const char*)tile + off);
}

// ---------------- kernel 0: fused prep = fp32->bf16 convert (q, kv) + W transpose ----------------
// grid (2048, 3): y=0 convert q block x; y=1 convert kv block x; y=2 (x<768) wtrans.
__global__ __launch_bounds__(256) void k_prep(const float* __restrict__ q,
                                              const float* __restrict__ kv,
                                              const float* __restrict__ Wq,
                                              const float* __restrict__ Wk,
                                              const float* __restrict__ Wv,
                                              uint16_t* __restrict__ oq,
                                              uint16_t* __restrict__ okv,
                                              uint16_t* __restrict__ Wt) {
  __shared__ uint16_t t[64][72];
  int y = blockIdx.y;
  int tid = threadIdx.x;
  if (y < 2) {
    const float* src = y ? kv : q;
    uint16_t* dst = y ? okv : oq;
    size_t i = ((size_t)blockIdx.x * 256 + tid) * 8;
    float4 a = *(const float4*)(src + i);
    float4 bb = *(const float4*)(src + i + 4);
    uint16_t r[8];
    r[0] = f2bf(a.x); r[1] = f2bf(a.y); r[2] = f2bf(a.z); r[3] = f2bf(a.w);
    r[4] = f2bf(bb.x); r[5] = f2bf(bb.y); r[6] = f2bf(bb.z); r[7] = f2bf(bb.w);
    *(uint4*)(dst + i) = *(uint4*)r;
    return;
  }
  int x = blockIdx.x;
  if (x >= 768) return;
  int by = x >> 4;                        // 0..47 = mat*16 + h
  int bx = x & 15;                        // d-block
  int mat = by >> 4;
  int h = by & 15;
  int d0 = bx * 64;
  const float* W = (mat == 0) ? Wq : (mat == 1) ? Wk : Wv;
  for (int p = 0; p < 4; p++) {
    int idx = tid + p * 256;
    int row = idx >> 4;
    int c4 = idx & 15;
    float4 v = *(const float4*)(W + ((size_t)h * 1024 + d0 + row) * 64 + c4 * 4);
    t[c4 * 4 + 0][row] = f2bf(v.x);
    t[c4 * 4 + 1][row] = f2bf(v.y);
    t[c4 * 4 + 2][row] = f2bf(v.z);
    t[c4 * 4 + 3][row] = f2bf(v.w);
  }
  __syncthreads();
  int n = tid >> 2, dc = tid & 3;
  uint16_t tmp[16];
  for (int i = 0; i < 16; i++) tmp[i] = t[n][dc * 16 + i];
  uint16_t* dst = Wt + ((size_t)(mat * 16 + h) * 64 + n) * 1024 + d0 + dc * 16;
  *(uint4*)(dst) = *(uint4*)(tmp);
  *(uint4*)(dst + 8) = *(uint4*)(tmp + 8);
}

// ---------------- kernel 1: QKV projection GEMM (single head per block, R1 geometry) ----------------
// Per block: 128(M) x 64(N=DH) for one (mat,h). K=1024, BK=64, double-buffered.
// LDS 48KB -> 3 blocks/CU with __launch_bounds__(256,3). Grid (32, 48) = 1536 blocks.
__global__ __launch_bounds__(256, 3) void k_proj(const uint16_t* __restrict__ Xq,
                                                 const uint16_t* __restrict__ Xkv,
                                                 const uint16_t* __restrict__ Wt,
                                                 const float* __restrict__ bq,
                                                 const float* __restrict__ bk,
                                                 const float* __restrict__ bv,
                                                 uint16_t* __restrict__ Qm,
                                                 uint16_t* __restrict__ Km,
                                                 uint16_t* __restrict__ Vtm) {
  __shared__ uint16_t At[2][128 * 64];    // 32 KB
  __shared__ uint16_t Bt[2][64 * 64];     // 16 KB
  int mb = blockIdx.x;
  int mat = blockIdx.y >> 4;
  int h = blockIdx.y & 15;
  int tid = threadIdx.x, w = tid >> 6, lane = tid & 63;
  const uint16_t* X = (mat == 0) ? Xq : Xkv;
  const uint16_t* Wh = Wt + (size_t)(mat * 16 + h) * (64 * 1024);
  const float* bias = (mat == 0) ? bq : (mat == 1) ? bk : bv;
  int m0 = mb * 128;
  int rgrp = lane >> 4, cl = lane & 15;

  f32x4 acc[2][4];
#pragma unroll
  for (int mf = 0; mf < 2; mf++)
#pragma unroll
    for (int nf = 0; nf < 4; nf++)
#pragma unroll
      for (int j = 0; j < 4; j++) acc[mf][nf][j] = 0.0f;

  // prologue: stage kt=0
#pragma unroll
  for (int i = 0; i < 4; i++) {
    int r0 = w * 32 + i * 8;
    stage8(X + (size_t)(m0 + r0) * 1024, 1024, &At[0][r0 * 64], lane);
  }
#pragma unroll
  for (int i = 0; i < 2; i++) {
    int r0 = w * 16 + i * 8;
    stage8(Wh + (size_t)r0 * 1024, 1024, &Bt[0][r0 * 64], lane);
  }

  for (int kt = 0; kt < 16; kt++) {
    __syncthreads();           // staged tile kt ready (implicit vmcnt drain)
    if (kt < 15) {
      int nb = (kt + 1) & 1, k0 = (kt + 1) * 64;
#pragma unroll
      for (int i = 0; i < 4; i++) {
        int r0 = w * 32 + i * 8;
        stage8(X + (size_t)(m0 + r0) * 1024 + k0, 1024, &At[nb][r0 * 64], lane);
      }
#pragma unroll
      for (int i = 0; i < 2; i++) {
        int r0 = w * 16 + i * 8;
        stage8(Wh + (size_t)r0 * 1024 + k0, 1024, &Bt[nb][r0 * 64], lane);
      }
    }
    const uint16_t* a_t = At[kt & 1];
    const uint16_t* b_t = Bt[kt & 1];
    bf16x8 af[2][2], bfr[4][2];
#pragma unroll
    for (int mf = 0; mf < 2; mf++)
#pragma unroll
      for (int ks = 0; ks < 2; ks++)
        af[mf][ks] = frag_read(a_t, w * 32 + mf * 16 + cl, ks * 4 + rgrp);
#pragma unroll
    for (int nf = 0; nf < 4; nf++)
#pragma unroll
      for (int ks = 0; ks < 2; ks++)
        bfr[nf][ks] = frag_read(b_t, nf * 16 + cl, ks * 4 + rgrp);
    __builtin_amdgcn_s_setprio(1);
#pragma unroll
    for (int mf = 0; mf < 2; mf++)
#pragma unroll
      for (int nf = 0; nf < 4; nf++)
#pragma unroll
        for (int ks = 0; ks < 2; ks++)
          acc[mf][nf] = __builtin_amdgcn_mfma_f32_16x16x32_bf16(af[mf][ks], bfr[nf][ks], acc[mf][nf], 0, 0, 0);
    __builtin_amdgcn_s_setprio(0);
  }

  // epilogue: add bias, write bf16. C/D: col=lane&15, row=(lane>>4)*4+j
#pragma unroll
  for (int mf = 0; mf < 2; mf++)
#pragma unroll
    for (int nf = 0; nf < 4; nf++) {
      int col = nf * 16 + cl;
      float bb = bias[h * 64 + col];
      if (mat < 2) {
        uint16_t* dstbuf = (mat == 0) ? Qm : Km;
#pragma unroll
        for (int j = 0; j < 4; j++) {
          int row = m0 + w * 32 + mf * 16 + rgrp * 4 + j;
          int b = row >> 11, s = row & 2047;
          dstbuf[((size_t)(b * 16 + h) * 2048 + s) * 64 + col] = f2bf(acc[mf][nf][j] + bb);
        }
      } else {
        int row0 = m0 + w * 32 + mf * 16 + rgrp * 4;
        int b = row0 >> 11, s0 = row0 & 2047;
        uint16_t pk[4];
#pragma unroll
        for (int j = 0; j < 4; j++) pk[j] = f2bf(acc[mf][nf][j] + bb);
        uint16_t* dst = Vtm + ((size_t)(b * 16 + h) * 64 + col) * 2048 + s0;
        *(uint64_t*)dst = *(uint64_t*)pk;
      }
    }
}

// ---------------- kernel 1b: mask nonzero partial bitmasks, streaming layout ----------------
// 256 blocks: idx -> b = idx>>7, rg = idx&127 (16-row group). Each block streams a
// CONTIGUOUS 128KB chunk (16 q-rows x 2048 t) and emits one 32-bit mask: bit tt set
// if any nonzero in t-columns [tt*64, tt*64+64). One word per block -- no atomics.
__global__ __launch_bounds__(256) void k_maskflag(const float* __restrict__ mask,
                                                  uint32_t* __restrict__ flagsP) {
  __shared__ uint32_t wm[4];
  int idx = blockIdx.x;
  int b = idx >> 7, rg = idx & 127;
  const float* base = mask + ((size_t)b * 2048 + rg * 16) * 2048;
  int tid = threadIdx.x;
  uint32_t m = 0;
  for (int it = 0; it < 32; it++) {
    int lin = it * 256 + tid;             // float4 index within chunk, 0..8191
    float4 v = *(const float4*)(base + (size_t)lin * 4);
    int tt = ((lin * 4) & 2047) >> 6;
    if ((v.x != 0.0f) | (v.y != 0.0f) | (v.z != 0.0f) | (v.w != 0.0f)) m |= (1u << tt);
  }
#pragma unroll
  for (int d = 1; d < 64; d <<= 1) m |= (uint32_t)__shfl_xor((int)m, d, 64);
  if ((tid & 63) == 0) wm[tid >> 6] = m;
  __syncthreads();
  if (tid == 0) flagsP[idx] = wm[0] | wm[1] | wm[2] | wm[3];
}

// ---------------- kernel 2: flash attention v15 (R15-exact, best validated) ----------------
// 1024 blocks (LDS 40KB), 4 waves x 16 q-rows. Fixed-max softmax (R9), K+V LDS dbuf
// (R2/R9 staging), P-LDS+fence, mask-skip via partial bitmask OR (R14/R15),
// mask-first issue order (R13), early-V ds_reads (R12), XCD-local bh (R13).
__global__ __launch_bounds__(256, 2) void k_attn(const uint16_t* __restrict__ Qm,
                                                 const uint16_t* __restrict__ Km,
                                                 const uint16_t* __restrict__ Vtm,
                                                 const float* __restrict__ mask,
                                                 const uint32_t* __restrict__ flagsP,
                                                 float* __restrict__ out) {
  __shared__ uint16_t Kt[2][64 * 64];     // 16 KB
  __shared__ uint16_t Vt[2][64 * 64];     // 16 KB
  __shared__ uint16_t Pt[4][16 * 64];     // 8 KB
  int bid = blockIdx.x;
  int xcd = bid & 7, jj = bid >> 3;       // jj 0..127
  int bh = xcd * 4 + (jj & 3);            // 4 bh per XCD (2MB K/V resident in its L2)
  int qb = jj >> 2;                       // 0..31
  int b = bh >> 4, h = bh & 15;
  int tid = threadIdx.x, w = tid >> 6, lane = tid & 63;
  int q0 = qb * 64 + w * 16;              // 16 q-rows per wave
  int rgrp = lane >> 4, cl = lane & 15;
  const uint16_t* Qbh = Qm + (size_t)bh * (2048 * 64);
  const uint16_t* Kbh = Km + (size_t)bh * (2048 * 64);
  const uint16_t* Vbh = Vtm + (size_t)bh * (64 * 2048);
  const float* mrp = mask + ((size_t)b * 2048 + (q0 + cl)) * 2048;
  uint16_t* Pw = Pt[w];

  const float L2E  = 1.4426950408889634f;
  const float SCL2 = 0.125f * 1.4426950408889634f;
  const float SH2  = -2.0f * 1.4426950408889634f;  // fixed shift: p = exp(S' - 2)

  // mask-tile bits for this block's 64 q-rows: OR of 4 row-group partials
  const uint32_t* fp = flagsP + b * 128 + qb * 4;
  uint32_t bits = fp[0] | fp[1] | fp[2] | fp[3];

  // Q fragments (B-operand of swapped QK^T), registers for all tiles
  bf16x8 qfr[2];
#pragma unroll
  for (int ks = 0; ks < 2; ks++)
    qfr[ks] = *(const bf16x8*)(Qbh + (size_t)(q0 + cl) * 64 + (ks * 4 + rgrp) * 8);

  f32x4 oacc[4];
  float lrow = 0.0f;
#pragma unroll
  for (int dhf = 0; dhf < 4; dhf++)
#pragma unroll
    for (int j = 0; j < 4; j++) oacc[dhf][j] = 0.0f;

  // prologue: stage tile 0 (each wave: K rows w*16.., V rows (dh) w*16..)
#pragma unroll
  for (int i = 0; i < 2; i++) {
    int r0 = w * 16 + i * 8;
    stage8(Kbh + (size_t)r0 * 64, 64, &Kt[0][r0 * 64], lane);
    stage8(Vbh + (size_t)r0 * 2048, 2048, &Vt[0][r0 * 64], lane);
  }

  for (int ti = 0; ti < 32; ti++) {
    __syncthreads();           // tile ti staged; prev tile's LDS reads done
    int t0 = ti * 64;
    bool hasmask = (bits >> ti) & 1;      // wave-uniform

    // mask loads FIRST (oldest in vmcnt queue), skipped when tile all-zero
    float4 mv[4];
    if (hasmask) {
#pragma unroll
      for (int tf = 0; tf < 4; tf++)
        mv[tf] = *(const float4*)(mrp + t0 + tf * 16 + rgrp * 4);
    }

    // stage next tile (stays in flight until next barrier)
    if (ti < 31) {
      int nb = (ti + 1) & 1, t0n = t0 + 64;
#pragma unroll
      for (int i = 0; i < 2; i++) {
        int r0 = w * 16 + i * 8;
        stage8(Kbh + (size_t)(t0n + r0) * 64, 64, &Kt[nb][r0 * 64], lane);
        stage8(Vbh + (size_t)r0 * 2048 + t0n, 2048, &Vt[nb][r0 * 64], lane);
      }
    }
    const uint16_t* kt = Kt[ti & 1];
    const uint16_t* vt = Vt[ti & 1];

    // S^T = K Q^T : lane holds S[q=cl][t=tf*16+rgrp*4+j]
    f32x4 sc[4];
#pragma unroll
    for (int tf = 0; tf < 4; tf++)
#pragma unroll
      for (int j = 0; j < 4; j++) sc[tf][j] = 0.0f;
    bf16x8 kf[4][2];
#pragma unroll
    for (int tf = 0; tf < 4; tf++)
#pragma unroll
      for (int ks = 0; ks < 2; ks++)
        kf[tf][ks] = frag_read(kt, tf * 16 + cl, ks * 4 + rgrp);
    __builtin_amdgcn_s_setprio(1);
#pragma unroll
    for (int tf = 0; tf < 4; tf++)
#pragma unroll
      for (int ks = 0; ks < 2; ks++)
        sc[tf] = __builtin_amdgcn_mfma_f32_16x16x32_bf16(kf[tf][ks], qfr[ks], sc[tf], 0, 0, 0);
    __builtin_amdgcn_s_setprio(0);

    // V fragment ds_reads EARLY: LDS latency overlaps the softmax VALU
    bf16x8 vf[4][2];
#pragma unroll
    for (int dhf = 0; dhf < 4; dhf++)
#pragma unroll
      for (int ks = 0; ks < 2; ks++)
        vf[dhf][ks] = frag_read(vt, dhf * 16 + cl, ks * 4 + rgrp);

    // scale+mask only when needed; otherwise fold 0.125 into the exp2 slope
    float eA = L2E;
    if (hasmask) {
#pragma unroll
      for (int tf = 0; tf < 4; tf++) {
        sc[tf][0] = fmaf(sc[tf][0], 0.125f, mv[tf].x);
        sc[tf][1] = fmaf(sc[tf][1], 0.125f, mv[tf].y);
        sc[tf][2] = fmaf(sc[tf][2], 0.125f, mv[tf].z);
        sc[tf][3] = fmaf(sc[tf][3], 0.125f, mv[tf].w);
      }
    } else {
      eA = SCL2;
    }

    // fixed-max: P = exp2(sc*eA + SH2); per-lane l accumulation; pack; b64 writes
#pragma unroll
    for (int tf = 0; tf < 4; tf++) {
      float p0 = __builtin_amdgcn_exp2f(fmaf(sc[tf][0], eA, SH2));
      float p1 = __builtin_amdgcn_exp2f(fmaf(sc[tf][1], eA, SH2));
      float p2 = __builtin_amdgcn_exp2f(fmaf(sc[tf][2], eA, SH2));
      float p3 = __builtin_amdgcn_exp2f(fmaf(sc[tf][3], eA, SH2));
      lrow += (p0 + p1) + (p2 + p3);
      uint2 pv;
      pv.x = cvtpk_bf16(p0, p1);
      pv.y = cvtpk_bf16(p2, p3);
      int off = cl * 128 + ((((tf * 2 + (rgrp >> 1)) << 4)) ^ ((cl & 7) << 4)) + (rgrp & 1) * 8;
      *(uint2*)((char*)Pw + off) = pv;
    }

    // order P stores before P fragment loads (same-wave DS ops are in-order in HW)
    asm volatile("" ::: "memory");

    // O^T += V^T P : A = V^T rows (dh, preloaded), B = P rows (q), k = t
    bf16x8 pf[2];
#pragma unroll
    for (int ks = 0; ks < 2; ks++)
      pf[ks] = frag_read(Pw, cl, ks * 4 + rgrp);
    __builtin_amdgcn_s_setprio(1);
#pragma unroll
    for (int dhf = 0; dhf < 4; dhf++)
#pragma unroll
      for (int ks = 0; ks < 2; ks++)
        oacc[dhf] = __builtin_amdgcn_mfma_f32_16x16x32_bf16(vf[dhf][ks], pf[ks], oacc[dhf], 0, 0, 0);
    __builtin_amdgcn_s_setprio(0);
  }

  // epilogue: reduce l across the 4 rgrp lanes (same q), then write out
  lrow += __shfl_xor(lrow, 16, 64);
  lrow += __shfl_xor(lrow, 32, 64);
  float inv = __builtin_amdgcn_rcpf(lrow);
  float* orow = out + ((size_t)b * 2048 + (q0 + cl)) * 1024 + h * 64;
#pragma unroll
  for (int dhf = 0; dhf < 4; dhf++) {
    float4 o;
    o.x = oacc[dhf][0] * inv;
    o.y = oacc[dhf][1] * inv;
    o.z = oacc[dhf][2] * inv;
    o.w = oacc[dhf][3] * inv;
    *(float4*)(orow + dhf * 16 + rgrp * 4) = o;
  }
}

extern "C" void kernel_launch(void* const* d_in, const int* in_sizes, int n_in,
                              void* d_out, int out_size, void* d_ws, size_t ws_size,
                              hipStream_t stream) {
  const float* q    = (const float*)d_in[0];
  const float* kv   = (const float*)d_in[1];
  const float* mask = (const float*)d_in[2];
  const float* Wq   = (const float*)d_in[3];
  const float* bq   = (const float*)d_in[4];
  const float* Wk   = (const float*)d_in[5];
  const float* bk   = (const float*)d_in[6];
  const float* Wv   = (const float*)d_in[7];
  const float* bv   = (const float*)d_in[8];
  float* out = (float*)d_out;

  // workspace (bf16 elems): Xq, Xkv, Q, K, Vt (4,194,304 each), Wt (3,145,728).
  // After k_proj, Xq is dead -> mask partial bitmasks (256 u32) overlay its start.
  uint16_t* Xq  = (uint16_t*)d_ws;
  uint16_t* Xkv = Xq + 4194304;
  uint16_t* Qm  = Xkv + 4194304;
  uint16_t* Km  = Qm + 4194304;
  uint16_t* Vtm = Km + 4194304;
  uint16_t* Wt  = Vtm + 4194304;
  uint32_t* flagsP = (uint32_t*)Xq;

  hipLaunchKernelGGL(k_prep, dim3(2048, 3), dim3(256), 0, stream,
                     q, kv, Wq, Wk, Wv, Xq, Xkv, Wt);
  hipLaunchKernelGGL(k_proj, dim3(32, 48), dim3(256), 0, stream,
                     Xq, Xkv, Wt, bq, bk, bv, Qm, Km, Vtm);
  hipLaunchKernelGGL(k_maskflag, dim3(256), dim3(256), 0, stream, mask, flagsP);
  hipLaunchKernelGGL(k_attn, dim3(1024), dim3(256), 0, stream,
                     Qm, Km, Vtm, mask, flagsP, out);
}